// Round 6
// baseline (57.013 us; speedup 1.0000x reference)
//
#include <hip/hip_runtime.h>

// PointPillarsScatter: out[b][c][y][x] = sum_{p: coords[p]=(b,_,y,x)} vf[p][c]
// B=4, C=64, NY=496, NX=432, P=48000. Output (B,C,NY,NX) f32 ~219 MB.
//
// 3-kernel gather pipeline (R5: cooperative fusion removed — it fails graph
// capture, so timing always ran this path anyway; coop direct-launch was
// 395 us due to grid.sync oversubscription):
//   k1 init : head[cell] = -1, one int4 store per thread (837 blocks)
//   k2 build: per-pillar linked list via atomicExch (head/nxt in d_ws)
//   k3 gather: per block 256 cells x 64 ch; per thread 4 cells x 16 ch.
//              Direct int4 head load (no LDS, no barriers), chain walked once,
//              float4 vf loads, 16 x 1KB/wave NON-TEMPORAL float4 stores
//              (out has zero reuse -> keep L2 for head/nxt/vf).

#define CC 64
#define GNY 496
#define GNX 432
#define S_CELLS (GNY * GNX)         // 214272 (divisible by 256)
#define NUM_CELLS (4 * S_CELLS)     // 857088
#define NTILES (NUM_CELLS / 256)    // 3348

typedef float f4_t __attribute__((ext_vector_type(4)));

__global__ void pp_init_head(int4* __restrict__ head4) {
    int i = blockIdx.x * blockDim.x + threadIdx.x;   // exactly NUM_CELLS/4 threads
    head4[i] = make_int4(-1, -1, -1, -1);
}

__global__ void pp_build(const int* __restrict__ coords,
                         int* __restrict__ head,
                         int* __restrict__ nxt,
                         int P) {
    int p = blockIdx.x * blockDim.x + threadIdx.x;
    if (p >= P) return;
    int4 c = ((const int4*)coords)[p];               // (b, z, y, x)
    int s = (c.x * GNY + c.z) * GNX + c.w;
    nxt[p] = atomicExch(&head[s], p);
}

__global__ __launch_bounds__(256)
void pp_gather(const float4* __restrict__ vf4,
               const int* __restrict__ head,
               const int* __restrict__ nxt,
               float* __restrict__ out) {
    int t = threadIdx.x;
    int lane = t & 63;
    int cgp = t >> 6;                      // channel group: channels cgp*16..+15
    int tile = blockIdx.x;
    int s0 = tile * 256 + lane * 4;        // 4 consecutive cells
    int b = s0 / S_CELLS;                  // tiles never straddle batches
    int r0 = s0 - b * S_CELLS;

    // Direct coalesced head load: 64 distinct int4 per block; waves 1-3 hit L1.
    int4 h4 = ((const int4*)head)[tile * 64 + lane];
    int hh[4] = {h4.x, h4.y, h4.z, h4.w};

    float acc[4][16];
    #pragma unroll
    for (int cell = 0; cell < 4; ++cell)
        #pragma unroll
        for (int i = 0; i < 16; ++i)
            acc[cell][i] = 0.f;

    #pragma unroll
    for (int cell = 0; cell < 4; ++cell) {
        for (int p = hh[cell]; p >= 0; ) {
            int pn = nxt[p];
            int pb = p * 16 + cgp * 4;     // float4 index into vf
            #pragma unroll
            for (int j = 0; j < 4; ++j) {
                float4 v = vf4[pb + j];
                acc[cell][4 * j + 0] += v.x;
                acc[cell][4 * j + 1] += v.y;
                acc[cell][4 * j + 2] += v.z;
                acc[cell][4 * j + 3] += v.w;
            }
            p = pn;
        }
    }

    size_t outbase = (size_t)b * (CC * S_CELLS)
                   + (size_t)(cgp * 16) * S_CELLS + r0;
    #pragma unroll
    for (int i = 0; i < 16; ++i) {
        f4_t o = {acc[0][i], acc[1][i], acc[2][i], acc[3][i]};
        __builtin_nontemporal_store(o, (f4_t*)&out[outbase + (size_t)i * S_CELLS]);
    }
}

extern "C" void kernel_launch(void* const* d_in, const int* in_sizes, int n_in,
                              void* d_out, int out_size, void* d_ws, size_t ws_size,
                              hipStream_t stream) {
    const float* vf     = (const float*)d_in[0];
    const int*   coords = (const int*)d_in[1];
    float*       out    = (float*)d_out;

    int P = in_sizes[1] / 4;                      // 48000

    size_t need = (size_t)(NUM_CELLS + P) * sizeof(int);
    if (ws_size < need) return;                   // cannot happen per harness sizing

    int* head = (int*)d_ws;
    int* nxt  = head + NUM_CELLS;

    pp_init_head<<<NUM_CELLS / 4 / 256, 256, 0, stream>>>((int4*)head);
    pp_build<<<(P + 255) / 256, 256, 0, stream>>>(coords, head, nxt, P);
    pp_gather<<<NTILES, 256, 0, stream>>>((const float4*)vf, head, nxt, out);
}

// Round 7
// 47.816 us; speedup vs baseline: 1.1923x; 1.1923x over previous
//
#include <hip/hip_runtime.h>

// PointPillarsScatter: out[b][c][y][x] = sum_{p: coords[p]=(b,_,y,x)} vf[p][c]
// B=4, C=64, NY=496, NX=432, P=48000. Output (B,C,NY,NX) f32 ~219 MB.
//
// Pipeline (R3-proven gather; R6 lesson: NO nontemporal stores — nt bypasses
// the L2 write path and cost ~25% of store BW):
//   k0 init : hipMemsetAsync(head, 0xFF) -> -1 ints, runs as 6.9 TB/s fill
//   k1 build: per-pillar linked list via atomicExch (head/nxt in d_ws)
//   k2 gather: per block 256 cells x 64 ch; per thread 4 cells x 16 ch.
//              Heads staged in LDS, chain walked once, float4 vf loads,
//              16 x 1KB/wave plain float4 stores.

#define CC 64
#define GNY 496
#define GNX 432
#define S_CELLS (GNY * GNX)         // 214272 (divisible by 256)
#define NUM_CELLS (4 * S_CELLS)     // 857088
#define NTILES (NUM_CELLS / 256)    // 3348

__global__ void pp_build(const int* __restrict__ coords,
                         int* __restrict__ head,
                         int* __restrict__ nxt,
                         int P) {
    int p = blockIdx.x * blockDim.x + threadIdx.x;
    if (p >= P) return;
    int4 c = ((const int4*)coords)[p];               // (b, z, y, x)
    int s = (c.x * GNY + c.z) * GNX + c.w;
    nxt[p] = atomicExch(&head[s], p);
}

__global__ __launch_bounds__(256)
void pp_gather(const float4* __restrict__ vf4,
               const int* __restrict__ head,
               const int* __restrict__ nxt,
               float* __restrict__ out) {
    __shared__ alignas(16) int lds[256];
    int t = threadIdx.x;
    lds[t] = head[blockIdx.x * 256 + t];
    __syncthreads();

    int lane = t & 63;
    int cgp = t >> 6;                      // channel group: channels cgp*16..+15
    int s0 = blockIdx.x * 256 + lane * 4;  // 4 consecutive cells
    int b = s0 / S_CELLS;                  // tiles never straddle batches
    int r0 = s0 - b * S_CELLS;

    int4 h4 = ((const int4*)lds)[lane];    // ds_read_b128
    int hh[4] = {h4.x, h4.y, h4.z, h4.w};

    float acc[4][16];
    #pragma unroll
    for (int cell = 0; cell < 4; ++cell)
        #pragma unroll
        for (int i = 0; i < 16; ++i)
            acc[cell][i] = 0.f;

    #pragma unroll
    for (int cell = 0; cell < 4; ++cell) {
        for (int p = hh[cell]; p >= 0; ) {
            int pn = nxt[p];
            int pb = p * 16 + cgp * 4;     // float4 index into vf
            #pragma unroll
            for (int j = 0; j < 4; ++j) {
                float4 v = vf4[pb + j];
                acc[cell][4 * j + 0] += v.x;
                acc[cell][4 * j + 1] += v.y;
                acc[cell][4 * j + 2] += v.z;
                acc[cell][4 * j + 3] += v.w;
            }
            p = pn;
        }
    }

    size_t outbase = (size_t)b * (CC * S_CELLS)
                   + (size_t)(cgp * 16) * S_CELLS + r0;
    #pragma unroll
    for (int i = 0; i < 16; ++i) {
        float4 o = make_float4(acc[0][i], acc[1][i], acc[2][i], acc[3][i]);
        *(float4*)&out[outbase + (size_t)i * S_CELLS] = o;
    }
}

extern "C" void kernel_launch(void* const* d_in, const int* in_sizes, int n_in,
                              void* d_out, int out_size, void* d_ws, size_t ws_size,
                              hipStream_t stream) {
    const float* vf     = (const float*)d_in[0];
    const int*   coords = (const int*)d_in[1];
    float*       out    = (float*)d_out;

    int P = in_sizes[1] / 4;                      // 48000

    size_t need = (size_t)(NUM_CELLS + P) * sizeof(int);
    if (ws_size < need) return;                   // cannot happen per harness sizing

    int* head = (int*)d_ws;
    int* nxt  = head + NUM_CELLS;

    // head[cell] = -1 via byte-fill 0xFF (graph-capturable, ~6.9 TB/s).
    hipMemsetAsync(head, 0xFF, (size_t)NUM_CELLS * sizeof(int), stream);
    pp_build<<<(P + 255) / 256, 256, 0, stream>>>(coords, head, nxt, P);
    pp_gather<<<NTILES, 256, 0, stream>>>((const float4*)vf, head, nxt, out);
}

// Round 8
// 47.616 us; speedup vs baseline: 1.1974x; 1.0042x over previous
//
#include <hip/hip_runtime.h>

// PointPillarsScatter: out[b][c][y][x] = sum_{p: coords[p]=(b,_,y,x)} vf[p][c]
// B=4, C=64, NY=496, NX=432, P=48000. Output (B,C,NY,NX) f32 ~219 MB.
//
// Pipeline:
//   k0 init : hipMemsetAsync(head, 0xFF) -> -1 ints (~6.9 TB/s fill)
//   k1 build: per-pillar linked list via atomicExch (head/nxt in d_ws)
//   k2 gather: per block 256 cells x 64 ch; per thread 4 cells x 16 ch.
// R8 changes vs R7 (store path untouched — R6 proved nt-stores cost 25%):
//   - direct per-lane int4 head load (no LDS, no barrier): chain walk starts
//     at earliest possible cycle; 4x redundancy across waves is L1-served.
//   - INTERLEAVED 4-cell chain walk: one lock-step loop issues all 4 nxt
//     loads + 16 vf float4 loads per iteration (4 serialized L2/L3
//     round-trips -> 1). Iterations = max chain len, not sum.

#define CC 64
#define GNY 496
#define GNX 432
#define S_CELLS (GNY * GNX)         // 214272 (divisible by 256)
#define NUM_CELLS (4 * S_CELLS)     // 857088
#define NTILES (NUM_CELLS / 256)    // 3348

__global__ void pp_build(const int* __restrict__ coords,
                         int* __restrict__ head,
                         int* __restrict__ nxt,
                         int P) {
    int p = blockIdx.x * blockDim.x + threadIdx.x;
    if (p >= P) return;
    int4 c = ((const int4*)coords)[p];               // (b, z, y, x)
    int s = (c.x * GNY + c.z) * GNX + c.w;
    nxt[p] = atomicExch(&head[s], p);
}

__global__ __launch_bounds__(256)
void pp_gather(const float4* __restrict__ vf4,
               const int4* __restrict__ head4,
               const int* __restrict__ nxt,
               float* __restrict__ out) {
    int t = threadIdx.x;
    int lane = t & 63;
    int cgp = t >> 6;                      // channel group: channels cgp*16..+15
    int tile = blockIdx.x;
    int s0 = tile * 256 + lane * 4;        // 4 consecutive cells
    int b = s0 / S_CELLS;                  // tiles never straddle batches
    int r0 = s0 - b * S_CELLS;
    int cbase = cgp * 4;                   // float4-index offset into vf row

    // Direct head load: issues immediately, no barrier. 64 distinct int4 per
    // block; waves 1..3 hit L1.
    int4 h4 = head4[tile * 64 + lane];
    int p0 = h4.x, p1 = h4.y, p2 = h4.z, p3 = h4.w;

    float acc[4][16];
    #pragma unroll
    for (int cell = 0; cell < 4; ++cell)
        #pragma unroll
        for (int i = 0; i < 16; ++i)
            acc[cell][i] = 0.f;

    // Interleaved chain walk: all 4 cells advance in lock-step; the 4 nxt
    // loads and up-to-16 vf4 loads per iteration are independent and issue
    // back-to-back (one latency round-trip per iteration, not four).
    while ((p0 >= 0) | (p1 >= 0) | (p2 >= 0) | (p3 >= 0)) {
        int q0 = p0, q1 = p1, q2 = p2, q3 = p3;
        if (q0 >= 0) p0 = nxt[q0];
        if (q1 >= 0) p1 = nxt[q1];
        if (q2 >= 0) p2 = nxt[q2];
        if (q3 >= 0) p3 = nxt[q3];
        if (q0 >= 0) {
            int pb = q0 * 16 + cbase;
            #pragma unroll
            for (int j = 0; j < 4; ++j) {
                float4 v = vf4[pb + j];
                acc[0][4*j+0] += v.x; acc[0][4*j+1] += v.y;
                acc[0][4*j+2] += v.z; acc[0][4*j+3] += v.w;
            }
        }
        if (q1 >= 0) {
            int pb = q1 * 16 + cbase;
            #pragma unroll
            for (int j = 0; j < 4; ++j) {
                float4 v = vf4[pb + j];
                acc[1][4*j+0] += v.x; acc[1][4*j+1] += v.y;
                acc[1][4*j+2] += v.z; acc[1][4*j+3] += v.w;
            }
        }
        if (q2 >= 0) {
            int pb = q2 * 16 + cbase;
            #pragma unroll
            for (int j = 0; j < 4; ++j) {
                float4 v = vf4[pb + j];
                acc[2][4*j+0] += v.x; acc[2][4*j+1] += v.y;
                acc[2][4*j+2] += v.z; acc[2][4*j+3] += v.w;
            }
        }
        if (q3 >= 0) {
            int pb = q3 * 16 + cbase;
            #pragma unroll
            for (int j = 0; j < 4; ++j) {
                float4 v = vf4[pb + j];
                acc[3][4*j+0] += v.x; acc[3][4*j+1] += v.y;
                acc[3][4*j+2] += v.z; acc[3][4*j+3] += v.w;
            }
        }
    }

    size_t outbase = (size_t)b * (CC * S_CELLS)
                   + (size_t)(cgp * 16) * S_CELLS + r0;
    #pragma unroll
    for (int i = 0; i < 16; ++i) {
        float4 o = make_float4(acc[0][i], acc[1][i], acc[2][i], acc[3][i]);
        *(float4*)&out[outbase + (size_t)i * S_CELLS] = o;
    }
}

extern "C" void kernel_launch(void* const* d_in, const int* in_sizes, int n_in,
                              void* d_out, int out_size, void* d_ws, size_t ws_size,
                              hipStream_t stream) {
    const float* vf     = (const float*)d_in[0];
    const int*   coords = (const int*)d_in[1];
    float*       out    = (float*)d_out;

    int P = in_sizes[1] / 4;                      // 48000

    size_t need = (size_t)(NUM_CELLS + P) * sizeof(int);
    if (ws_size < need) return;                   // cannot happen per harness sizing

    int* head = (int*)d_ws;
    int* nxt  = head + NUM_CELLS;

    // head[cell] = -1 via byte-fill 0xFF (graph-capturable, ~6.9 TB/s).
    hipMemsetAsync(head, 0xFF, (size_t)NUM_CELLS * sizeof(int), stream);
    pp_build<<<(P + 255) / 256, 256, 0, stream>>>(coords, head, nxt, P);
    pp_gather<<<NTILES, 256, 0, stream>>>((const float4*)vf, (const int4*)head,
                                          nxt, out);
}